// Round 1
// baseline (2023.865 us; speedup 1.0000x reference)
//
#include <hip/hip_runtime.h>
#include <math.h>

namespace {
constexpr int E_TOTAL = 500000;
constexpr int ND = 128;   // node dim
constexpr int ED = 64;    // edge dim
constexpr int IN = 320;   // 2*ND + ED
constexpr int H  = 128;   // hidden
constexpr int TE = 16;    // edges per block
constexpr int PAD = 20;   // padded transposed-row length (floats): 16B-aligned, breaks bank conflicts
constexpr float EPS = 1e-5f;
}

// Thread j (0..127) owns hidden channel j. Block processes TE edges.
// catT[k][e] holds cat_feat[e][k] transposed so per-k reads over e are float4s.
// Rows 0..127 of catT are reused for the post-GELU h tile (x-features dead after GEMM1).
__global__ __launch_bounds__(128, 3) void edge_update_kernel(
    const float* __restrict__ x,
    const int*   __restrict__ ei,
    const float* __restrict__ ea,
    const float* __restrict__ W1, const float* __restrict__ b1,
    const float* __restrict__ g1, const float* __restrict__ be1,
    const float* __restrict__ W2, const float* __restrict__ b2,
    const float* __restrict__ Wg, const float* __restrict__ bg,
    const float* __restrict__ Wr, const float* __restrict__ br,
    const float* __restrict__ g2, const float* __restrict__ be2,
    float* __restrict__ out)
{
    __shared__ float catT[IN * PAD];     // 25.6 KB; rows 0..H-1 reused as hT after GEMM1
    __shared__ float red[2][TE][2];      // per-wave partial (sum, sumsq) per edge

    const int j    = threadIdx.x;        // hidden channel
    const int wv   = j >> 6;
    const int lane = j & 63;
    const long e0  = (long)blockIdx.x * TE;

    // ---------------- gather: catT[k][e] = [x[src] | x[dst] | ea][k] ----------------
    for (int e = 0; e < TE; ++e) {
        const int eg = (int)e0 + e;
        const int s  = ei[eg];            // row 0: src
        const int d  = ei[E_TOTAL + eg];  // row 1: dst
        catT[j * PAD + e]            = x[(long)s * ND + j];
        catT[(ND + j) * PAD + e]     = x[(long)d * ND + j];
        if (j < ED) catT[(2 * ND + j) * PAD + e] = ea[(long)eg * ED + j];
    }
    __syncthreads();

    // ---------------- GEMM1: h_pre = cat@W1 + b1, g_pre = cat@Wg + bg ----------------
    float acc1[TE], accg[TE];
    {
        const float bb1 = b1[j], bbg = bg[j];
        #pragma unroll
        for (int e = 0; e < TE; ++e) { acc1[e] = bb1; accg[e] = bbg; }
    }
    for (int k = 0; k < IN; ++k) {
        const float w1k = W1[k * H + j];   // coalesced, L2-resident
        const float wgk = Wg[k * H + j];
        const float* row = &catT[k * PAD];
        const float4 c0 = *(const float4*)(row);
        const float4 c1 = *(const float4*)(row + 4);
        const float4 c2 = *(const float4*)(row + 8);
        const float4 c3 = *(const float4*)(row + 12);
        const float c[TE] = {c0.x,c0.y,c0.z,c0.w, c1.x,c1.y,c1.z,c1.w,
                             c2.x,c2.y,c2.z,c2.w, c3.x,c3.y,c3.z,c3.w};
        #pragma unroll
        for (int e = 0; e < TE; ++e) {
            acc1[e] = fmaf(c[e], w1k, acc1[e]);
            accg[e] = fmaf(c[e], wgk, accg[e]);
        }
    }

    // ---------------- LN1 stats (reduce over 128 channels = 2 waves) ----------------
    #pragma unroll
    for (int e = 0; e < TE; ++e) {
        float s  = acc1[e];
        float s2 = s * s;
        #pragma unroll
        for (int off = 32; off > 0; off >>= 1) {
            s  += __shfl_down(s, off);
            s2 += __shfl_down(s2, off);
        }
        if (lane == 0) { red[wv][e][0] = s; red[wv][e][1] = s2; }
    }
    __syncthreads();   // also guarantees every wave is done reading cat x-rows

    float gate[TE];
    {
        const float gg = g1[j], bb = be1[j];
        #pragma unroll
        for (int e = 0; e < TE; ++e) {
            const float sum = red[0][e][0] + red[1][e][0];
            const float sq  = red[0][e][1] + red[1][e][1];
            const float m   = sum * (1.0f / H);
            float var = sq * (1.0f / H) - m * m;
            var = fmaxf(var, 0.0f);
            const float rs = rsqrtf(var + EPS);
            float hv = (acc1[e] - m) * rs * gg + bb;
            hv = hv * 0.5f * (1.0f + erff(hv * 0.70710678118654752f));  // exact GELU
            gate[e] = 1.0f / (1.0f + __expf(-accg[e]));                 // sigmoid gate
            catT[j * PAD + e] = hv;   // hT[k=j][e], aliases dead cat rows
        }
    }
    __syncthreads();

    // ---------------- GEMM2: update = h@W2 + b2, res = ea@Wr + br ----------------
    float accU[TE], accR[TE];
    {
        const float bb2 = b2[j], bbr = br[j];
        #pragma unroll
        for (int e = 0; e < TE; ++e) { accU[e] = bb2; accR[e] = bbr; }
    }
    for (int k = 0; k < H; ++k) {
        const float w2k = W2[k * H + j];
        const float* row = &catT[k * PAD];
        const float4 c0 = *(const float4*)(row);
        const float4 c1 = *(const float4*)(row + 4);
        const float4 c2 = *(const float4*)(row + 8);
        const float4 c3 = *(const float4*)(row + 12);
        const float c[TE] = {c0.x,c0.y,c0.z,c0.w, c1.x,c1.y,c1.z,c1.w,
                             c2.x,c2.y,c2.z,c2.w, c3.x,c3.y,c3.z,c3.w};
        #pragma unroll
        for (int e = 0; e < TE; ++e) accU[e] = fmaf(c[e], w2k, accU[e]);
    }
    for (int k = 0; k < ED; ++k) {
        const float wrk = Wr[k * H + j];
        const float* row = &catT[(2 * ND + k) * PAD];   // edge_attr rows, still live
        const float4 c0 = *(const float4*)(row);
        const float4 c1 = *(const float4*)(row + 4);
        const float4 c2 = *(const float4*)(row + 8);
        const float4 c3 = *(const float4*)(row + 12);
        const float c[TE] = {c0.x,c0.y,c0.z,c0.w, c1.x,c1.y,c1.z,c1.w,
                             c2.x,c2.y,c2.z,c2.w, c3.x,c3.y,c3.z,c3.w};
        #pragma unroll
        for (int e = 0; e < TE; ++e) accR[e] = fmaf(c[e], wrk, accR[e]);
    }
    #pragma unroll
    for (int e = 0; e < TE; ++e) accU[e] = accU[e] * gate[e] + accR[e];

    // ---------------- LN2 + store ----------------
    #pragma unroll
    for (int e = 0; e < TE; ++e) {
        float s  = accU[e];
        float s2 = s * s;
        #pragma unroll
        for (int off = 32; off > 0; off >>= 1) {
            s  += __shfl_down(s, off);
            s2 += __shfl_down(s2, off);
        }
        if (lane == 0) { red[wv][e][0] = s; red[wv][e][1] = s2; }
    }
    __syncthreads();
    {
        const float gg = g2[j], bb = be2[j];
        #pragma unroll
        for (int e = 0; e < TE; ++e) {
            const float sum = red[0][e][0] + red[1][e][0];
            const float sq  = red[0][e][1] + red[1][e][1];
            const float m   = sum * (1.0f / H);
            float var = sq * (1.0f / H) - m * m;
            var = fmaxf(var, 0.0f);
            const float rs = rsqrtf(var + EPS);
            out[(e0 + e) * H + j] = (accU[e] - m) * rs * gg + bb;
        }
    }
}

extern "C" void kernel_launch(void* const* d_in, const int* in_sizes, int n_in,
                              void* d_out, int out_size, void* d_ws, size_t ws_size,
                              hipStream_t stream) {
    const float* x   = (const float*)d_in[0];
    const int*   ei  = (const int*)  d_in[1];
    const float* ea  = (const float*)d_in[2];
    const float* W1  = (const float*)d_in[3];
    const float* b1  = (const float*)d_in[4];
    const float* g1  = (const float*)d_in[5];
    const float* be1 = (const float*)d_in[6];
    const float* W2  = (const float*)d_in[7];
    const float* b2  = (const float*)d_in[8];
    const float* Wg  = (const float*)d_in[9];
    const float* bg  = (const float*)d_in[10];
    const float* Wr  = (const float*)d_in[11];
    const float* br  = (const float*)d_in[12];
    const float* g2  = (const float*)d_in[13];
    const float* be2 = (const float*)d_in[14];
    float* out = (float*)d_out;

    const int grid = E_TOTAL / TE;   // 500000/16 = 31250, exact
    edge_update_kernel<<<grid, 128, 0, stream>>>(
        x, ei, ea, W1, b1, g1, be1, W2, b2, Wg, bg, Wr, br, g2, be2, out);
}

// Round 2
// 643.057 us; speedup vs baseline: 3.1473x; 3.1473x over previous
//
#include <hip/hip_runtime.h>
#include <hip/hip_bf16.h>
#include <math.h>

typedef __attribute__((ext_vector_type(8))) short short8;   // 8 bf16 (4 VGPRs)
typedef __attribute__((ext_vector_type(4))) float f32x4;    // MFMA C/D

namespace {
constexpr int E_TOTAL = 500000;
constexpr int ND  = 128;   // node dim
constexpr int ED  = 64;    // edge dim
constexpr int KIN = 320;   // 2*ND + ED
constexpr int H   = 128;   // hidden
constexpr int ME  = 64;    // edges per block
constexpr int RS  = 328;   // catA row stride (shorts): 656B = 16B-aligned, +4-bank skew
constexpr float EPS = 1e-5f;
// d_ws offsets (in shorts): weights transposed [n][k], bf16
constexpr int OFF_W1T = 0;       // [128][320]
constexpr int OFF_WGT = 40960;   // [128][320]
constexpr int OFF_W2T = 81920;   // [128][128]
constexpr int OFF_WRT = 98304;   // [128][64]
}

__device__ __forceinline__ unsigned short f2bf(float f) {
  union { __hip_bfloat16 h; unsigned short u; } cv;
  cv.h = __float2bfloat16(f);   // RNE
  return cv.u;
}
__device__ __forceinline__ unsigned pack2(float a, float b) {
  return (unsigned)f2bf(a) | ((unsigned)f2bf(b) << 16);
}

// One-shot (per launch) weight prep: fp32 [K][N] -> bf16 transposed [N][K] in ws.
__global__ void prep_weights(const float* __restrict__ W1, const float* __restrict__ Wg,
                             const float* __restrict__ W2, const float* __restrict__ Wr,
                             short* __restrict__ wt) {
  const int t = blockIdx.x * 256 + threadIdx.x;
  if (t < 40960) {                       // W1T / WgT: n in [0,128), k in [0,320)
    const int n = t / KIN, k = t % KIN;
    wt[OFF_W1T + t] = (short)f2bf(W1[k * H + n]);
    wt[OFF_WGT + t] = (short)f2bf(Wg[k * H + n]);
  }
  if (t < 16384) {                       // W2T: [128][128]
    const int n = t / H, k = t % H;
    wt[OFF_W2T + t] = (short)f2bf(W2[k * H + n]);
  }
  if (t < 8192) {                        // WrT: [128][64]
    const int n = t / ED, k = t % ED;
    wt[OFF_WRT + t] = (short)f2bf(Wr[k * H + n]);
  }
}

// Block: 256 threads = 4 waves, 64 edges. Wave w owns cols [32w, 32w+32) (2 N-tiles)
// for ALL 4 M-tiles -> each weight element is read exactly once per block (L2-resident).
// catA: bf16 [m][k] A-fragment layout; rows k<128 reused for h after GEMM1.
__global__ __launch_bounds__(256, 2) void edge_mfma_kernel(
    const float* __restrict__ x, const int* __restrict__ ei, const float* __restrict__ ea,
    const short* __restrict__ wt,
    const float* __restrict__ b1, const float* __restrict__ g1, const float* __restrict__ be1,
    const float* __restrict__ b2, const float* __restrict__ bg, const float* __restrict__ br,
    const float* __restrict__ g2, const float* __restrict__ be2,
    float* __restrict__ out)
{
  __shared__ short catA[ME * RS];   // 41984 B
  __shared__ float red[ME][8];      // per-row {s,q} x 4 waves
  __shared__ int   sidx[ME], didx[ME];

  const int t    = threadIdx.x;
  const int w    = t >> 6;
  const int lane = t & 63;
  const int g    = lane >> 4;   // quad
  const int l15  = lane & 15;
  const long e0  = (long)blockIdx.x * ME;

  if (t < ME) {
    long eg = e0 + t; if (eg >= E_TOTAL) eg = E_TOTAL - 1;
    sidx[t] = ei[eg];
  } else if (t < 2 * ME) {
    long eg = e0 + (t - ME); if (eg >= E_TOTAL) eg = E_TOTAL - 1;
    didx[t - ME] = ei[E_TOTAL + eg];
  }
  __syncthreads();

  // ---- gather: catA[e][k] = bf16([x[src] | x[dst] | ea]) ----
  {
    const int c = lane << 1;                  // 0..126, float2 per lane = full row per wave
    for (int i = 0; i < 16; ++i) {
      const int e = i * 4 + w;
      const float2 xs = *(const float2*)(x + (long)sidx[e] * ND + c);
      const float2 xd = *(const float2*)(x + (long)didx[e] * ND + c);
      *(unsigned*)&catA[e * RS + c]      = pack2(xs.x, xs.y);
      *(unsigned*)&catA[e * RS + ND + c] = pack2(xd.x, xd.y);
    }
    const int e8 = t >> 5;
    const int c2 = (t & 31) << 1;
    for (int i = 0; i < 8; ++i) {
      const int e = i * 8 + e8;
      long eg = e0 + e; if (eg >= E_TOTAL) eg = E_TOTAL - 1;
      const float2 v = *(const float2*)(ea + eg * ED + c2);
      *(unsigned*)&catA[e * RS + 2 * ND + c2] = pack2(v.x, v.y);
    }
  }
  __syncthreads();

  const int col0 = w * 32 + l15;        // N-tile 0 col
  const int col1 = w * 32 + 16 + l15;   // N-tile 1 col

  // ---- GEMM1: h_pre = cat@W1 + b1 ; g_pre = cat@Wg + bg ----
  f32x4 accH[4][2], accG[4][2];
  {
    const float bh0 = b1[col0], bh1 = b1[col1];
    const float bg0 = bg[col0], bg1 = bg[col1];
    #pragma unroll
    for (int mt = 0; mt < 4; ++mt) {
      accH[mt][0] = (f32x4){bh0, bh0, bh0, bh0};
      accH[mt][1] = (f32x4){bh1, bh1, bh1, bh1};
      accG[mt][0] = (f32x4){bg0, bg0, bg0, bg0};
      accG[mt][1] = (f32x4){bg1, bg1, bg1, bg1};
    }
  }
  {
    const short* pW1a = wt + OFF_W1T + col0 * KIN + g * 8;
    const short* pW1b = wt + OFF_W1T + col1 * KIN + g * 8;
    const short* pWga = wt + OFF_WGT + col0 * KIN + g * 8;
    const short* pWgb = wt + OFF_WGT + col1 * KIN + g * 8;
    for (int ks = 0; ks < KIN / 32; ++ks) {
      const int ko = ks * 32 + g * 8;
      short8 a[4];
      #pragma unroll
      for (int mt = 0; mt < 4; ++mt)
        a[mt] = *(const short8*)&catA[(mt * 16 + l15) * RS + ko];
      const short8 bW1a = *(const short8*)(pW1a + ks * 32);
      const short8 bW1b = *(const short8*)(pW1b + ks * 32);
      const short8 bWga = *(const short8*)(pWga + ks * 32);
      const short8 bWgb = *(const short8*)(pWgb + ks * 32);
      #pragma unroll
      for (int mt = 0; mt < 4; ++mt) {
        accH[mt][0] = __builtin_amdgcn_mfma_f32_16x16x32_bf16(a[mt], bW1a, accH[mt][0], 0, 0, 0);
        accH[mt][1] = __builtin_amdgcn_mfma_f32_16x16x32_bf16(a[mt], bW1b, accH[mt][1], 0, 0, 0);
        accG[mt][0] = __builtin_amdgcn_mfma_f32_16x16x32_bf16(a[mt], bWga, accG[mt][0], 0, 0, 0);
        accG[mt][1] = __builtin_amdgcn_mfma_f32_16x16x32_bf16(a[mt], bWgb, accG[mt][1], 0, 0, 0);
      }
    }
  }

  // ---- LN1 stats: rows r = mt*16 + g*4 + reg; reduce wave's 32 cols then cross-wave ----
  #pragma unroll
  for (int mt = 0; mt < 4; ++mt) {
    f32x4 ps = accH[mt][0] + accH[mt][1];
    f32x4 pq = accH[mt][0] * accH[mt][0] + accH[mt][1] * accH[mt][1];
    #pragma unroll
    for (int off = 1; off < 16; off <<= 1) {
      #pragma unroll
      for (int r = 0; r < 4; ++r) {
        ps[r] += __shfl_xor(ps[r], off);
        pq[r] += __shfl_xor(pq[r], off);
      }
    }
    if (l15 == 0) {
      #pragma unroll
      for (int r = 0; r < 4; ++r) {
        red[mt * 16 + g * 4 + r][w * 2]     = ps[r];
        red[mt * 16 + g * 4 + r][w * 2 + 1] = pq[r];
      }
    }
  }
  __syncthreads();   // B1 — also orders all GEMM1 catA reads before h overwrite

  // ---- LN1 apply + exact GELU -> h to LDS (alias x[src] rows); sigmoid gate in regs ----
  {
    const float g1v0 = g1[col0], g1v1 = g1[col1];
    const float be10 = be1[col0], be11 = be1[col1];
    #pragma unroll
    for (int mt = 0; mt < 4; ++mt) {
      #pragma unroll
      for (int r = 0; r < 4; ++r) {
        const int row = mt * 16 + g * 4 + r;
        const float4 ra = *(const float4*)&red[row][0];
        const float4 rb = *(const float4*)&red[row][4];
        const float sum = ra.x + ra.z + rb.x + rb.z;
        const float sq  = ra.y + ra.w + rb.y + rb.w;
        const float m   = sum * (1.0f / H);
        float var = sq * (1.0f / H) - m * m;
        var = fmaxf(var, 0.0f);
        const float rs = rsqrtf(var + EPS);
        float h0 = (accH[mt][0][r] - m) * rs * g1v0 + be10;
        float h1 = (accH[mt][1][r] - m) * rs * g1v1 + be11;
        h0 = h0 * 0.5f * (1.0f + erff(h0 * 0.70710678118654752f));
        h1 = h1 * 0.5f * (1.0f + erff(h1 * 0.70710678118654752f));
        catA[row * RS + col0] = (short)f2bf(h0);
        catA[row * RS + col1] = (short)f2bf(h1);
        accG[mt][0][r] = 1.0f / (1.0f + __expf(-accG[mt][0][r]));
        accG[mt][1][r] = 1.0f / (1.0f + __expf(-accG[mt][1][r]));
      }
    }
  }
  __syncthreads();   // B2

  // ---- GEMM2: U = h@W2 + b2 ; R = ea@Wr + br ----
  f32x4 accU[4][2], accR[4][2];
  {
    const float bu0 = b2[col0], bu1 = b2[col1];
    const float br0 = br[col0], br1 = br[col1];
    #pragma unroll
    for (int mt = 0; mt < 4; ++mt) {
      accU[mt][0] = (f32x4){bu0, bu0, bu0, bu0};
      accU[mt][1] = (f32x4){bu1, bu1, bu1, bu1};
      accR[mt][0] = (f32x4){br0, br0, br0, br0};
      accR[mt][1] = (f32x4){br1, br1, br1, br1};
    }
  }
  {
    const short* pW2a = wt + OFF_W2T + col0 * H + g * 8;
    const short* pW2b = wt + OFF_W2T + col1 * H + g * 8;
    for (int ks = 0; ks < H / 32; ++ks) {
      const int ko = ks * 32 + g * 8;
      short8 a[4];
      #pragma unroll
      for (int mt = 0; mt < 4; ++mt)
        a[mt] = *(const short8*)&catA[(mt * 16 + l15) * RS + ko];
      const short8 b0 = *(const short8*)(pW2a + ks * 32);
      const short8 b1v = *(const short8*)(pW2b + ks * 32);
      #pragma unroll
      for (int mt = 0; mt < 4; ++mt) {
        accU[mt][0] = __builtin_amdgcn_mfma_f32_16x16x32_bf16(a[mt], b0, accU[mt][0], 0, 0, 0);
        accU[mt][1] = __builtin_amdgcn_mfma_f32_16x16x32_bf16(a[mt], b1v, accU[mt][1], 0, 0, 0);
      }
    }
    const short* pWra = wt + OFF_WRT + col0 * ED + g * 8;
    const short* pWrb = wt + OFF_WRT + col1 * ED + g * 8;
    for (int ks = 0; ks < ED / 32; ++ks) {
      const int ko = 2 * ND + ks * 32 + g * 8;
      short8 a[4];
      #pragma unroll
      for (int mt = 0; mt < 4; ++mt)
        a[mt] = *(const short8*)&catA[(mt * 16 + l15) * RS + ko];
      const short8 b0 = *(const short8*)(pWra + ks * 32);
      const short8 b1v = *(const short8*)(pWrb + ks * 32);
      #pragma unroll
      for (int mt = 0; mt < 4; ++mt) {
        accR[mt][0] = __builtin_amdgcn_mfma_f32_16x16x32_bf16(a[mt], b0, accR[mt][0], 0, 0, 0);
        accR[mt][1] = __builtin_amdgcn_mfma_f32_16x16x32_bf16(a[mt], b1v, accR[mt][1], 0, 0, 0);
      }
    }
  }

  // final = U*gate + R
  #pragma unroll
  for (int mt = 0; mt < 4; ++mt) {
    accU[mt][0] = accU[mt][0] * accG[mt][0] + accR[mt][0];
    accU[mt][1] = accU[mt][1] * accG[mt][1] + accR[mt][1];
  }

  // ---- LN2 ----
  #pragma unroll
  for (int mt = 0; mt < 4; ++mt) {
    f32x4 ps = accU[mt][0] + accU[mt][1];
    f32x4 pq = accU[mt][0] * accU[mt][0] + accU[mt][1] * accU[mt][1];
    #pragma unroll
    for (int off = 1; off < 16; off <<= 1) {
      #pragma unroll
      for (int r = 0; r < 4; ++r) {
        ps[r] += __shfl_xor(ps[r], off);
        pq[r] += __shfl_xor(pq[r], off);
      }
    }
    if (l15 == 0) {
      #pragma unroll
      for (int r = 0; r < 4; ++r) {
        red[mt * 16 + g * 4 + r][w * 2]     = ps[r];
        red[mt * 16 + g * 4 + r][w * 2 + 1] = pq[r];
      }
    }
  }
  __syncthreads();   // B3
  {
    const float g2v0 = g2[col0], g2v1 = g2[col1];
    const float be20 = be2[col0], be21 = be2[col1];
    #pragma unroll
    for (int mt = 0; mt < 4; ++mt) {
      #pragma unroll
      for (int r = 0; r < 4; ++r) {
        const int row = mt * 16 + g * 4 + r;
        const float4 ra = *(const float4*)&red[row][0];
        const float4 rb = *(const float4*)&red[row][4];
        const float sum = ra.x + ra.z + rb.x + rb.z;
        const float sq  = ra.y + ra.w + rb.y + rb.w;
        const float m   = sum * (1.0f / H);
        float var = sq * (1.0f / H) - m * m;
        var = fmaxf(var, 0.0f);
        const float rs = rsqrtf(var + EPS);
        const long eg = e0 + row;
        if (eg < E_TOTAL) {
          out[eg * H + col0] = (accU[mt][0][r] - m) * rs * g2v0 + be20;
          out[eg * H + col1] = (accU[mt][1][r] - m) * rs * g2v1 + be21;
        }
      }
    }
  }
}

extern "C" void kernel_launch(void* const* d_in, const int* in_sizes, int n_in,
                              void* d_out, int out_size, void* d_ws, size_t ws_size,
                              hipStream_t stream) {
  const float* x   = (const float*)d_in[0];
  const int*   ei  = (const int*)  d_in[1];
  const float* ea  = (const float*)d_in[2];
  const float* W1  = (const float*)d_in[3];
  const float* b1  = (const float*)d_in[4];
  const float* g1  = (const float*)d_in[5];
  const float* be1 = (const float*)d_in[6];
  const float* W2  = (const float*)d_in[7];
  const float* b2  = (const float*)d_in[8];
  const float* Wg  = (const float*)d_in[9];
  const float* bg  = (const float*)d_in[10];
  const float* Wr  = (const float*)d_in[11];
  const float* br  = (const float*)d_in[12];
  const float* g2  = (const float*)d_in[13];
  const float* be2 = (const float*)d_in[14];
  float* out = (float*)d_out;
  short* wt  = (short*)d_ws;   // 212992 B used

  prep_weights<<<160, 256, 0, stream>>>(W1, Wg, W2, Wr, wt);

  const int grid = (E_TOTAL + ME - 1) / ME;   // 7813
  edge_mfma_kernel<<<grid, 256, 0, stream>>>(
      x, ei, ea, wt, b1, g1, be1, b2, bg, br, g2, be2, out);
}